// Round 9
// baseline (307.997 us; speedup 1.0000x reference)
//
#include <hip/hip_runtime.h>
#include <hip/hip_bf16.h>

// Problem constants (fixed by reference): B=4, S=2048, DIN=DOUT=4096
constexpr int GM = 8192;   // B*S rows
constexpr int GN = 4096;   // DOUT
constexpr int GK = 4096;   // DIN

constexpr int BM = 256, BN = 256, BK = 64;
constexpr int NSTEP = GK / BK;              // 64 K-steps
constexpr int LDS_BYTES = 2 * BM * BK * 2;  // 65536: A-only double buffer

using bf16x8 = __attribute__((ext_vector_type(8))) __bf16;
using f32x4  = __attribute__((ext_vector_type(4))) float;

// -------------------- prep: A = bf16(x * in_scale) --------------------
__global__ __launch_bounds__(256) void prep_x_kernel(
    const float* __restrict__ x, const float* __restrict__ iscale,
    __bf16* __restrict__ A) {
  int e = (blockIdx.x * 256 + threadIdx.x) * 8;  // 8 elems/thread
  float4 v0 = *(const float4*)(x + e);
  float4 v1 = *(const float4*)(x + e + 4);
  int k = e & (GK - 1);
  float4 s0 = *(const float4*)(iscale + k);
  float4 s1 = *(const float4*)(iscale + k + 4);
  bf16x8 o;
  o[0] = (__bf16)(v0.x * s0.x);
  o[1] = (__bf16)(v0.y * s0.y);
  o[2] = (__bf16)(v0.z * s0.z);
  o[3] = (__bf16)(v0.w * s0.w);
  o[4] = (__bf16)(v1.x * s1.x);
  o[5] = (__bf16)(v1.y * s1.y);
  o[6] = (__bf16)(v1.z * s1.z);
  o[7] = (__bf16)(v1.w * s1.w);
  *(bf16x8*)(A + e) = o;
}

// -------------------- prep: Wbp = sign(W) in pre-fragmented MFMA layout ----
// Wbp[((rt*128 + kt)*64 + lane)*8 + e] = sign(W[rt*16 + (lane&15)]
//                                              [kt*32 + (lane>>4)*8 + e])
// so a wave's B-fragment (16 cols x 32 k) is ONE contiguous 1 KB load.
__device__ inline float sgnf(float v) {
  return (float)((v > 0.f) - (v < 0.f));
}

__global__ __launch_bounds__(256) void prep_w_kernel(
    const float* __restrict__ w, __bf16* __restrict__ Wbp) {
  int T = blockIdx.x * 256 + threadIdx.x;   // one 16-B fragment slice each
  int lane = T & 63;
  int kt = (T >> 6) & 127;
  int rt = T >> 13;
  int r = rt * 16 + (lane & 15);
  int k = kt * 32 + (lane >> 4) * 8;
  const float* src = w + (size_t)r * GK + k;
  float4 v0 = *(const float4*)(src);
  float4 v1 = *(const float4*)(src + 4);
  bf16x8 o;
  o[0] = (__bf16)sgnf(v0.x);
  o[1] = (__bf16)sgnf(v0.y);
  o[2] = (__bf16)sgnf(v0.z);
  o[3] = (__bf16)sgnf(v0.w);
  o[4] = (__bf16)sgnf(v1.x);
  o[5] = (__bf16)sgnf(v1.y);
  o[6] = (__bf16)sgnf(v1.z);
  o[7] = (__bf16)sgnf(v1.w);
  *(bf16x8*)(Wbp + (size_t)T * 8) = o;
}

// -------------------- GEMM: C[m][n] = sum_k A[m][k]*sign(W)[n][k] ----------
// B-BYPASSES-LDS structure. 256x256 tile, BK=64, 512 threads (2M x 4N waves,
// wave tile 128x64). LDS holds ONLY A (2 x 32 KiB buffers). B-fragments load
// global->reg from the pre-fragmented Wbp (1 KB coalesced per load), double-
// buffered one K-step ahead (bvE/bvO named sets, rule-20 static indexing).
// Per K-step t: [top] STAGE_A(t+1 -> other buf, 4 gload_lds); ds_read a0(8),
// 32 MFMA, ds_read a4(8), 32 MFMA (compiler schedules fine-grained lgkm);
// LOADB(t+2 -> this parity's set, 8 x 1KB, after last use); vmcnt(8); barrier.
// vmcnt(8) retire-set (queue-verified): keeps only B(t+2)'s 8 loads, drains
// A(t+1)+B(t+1). WAR: STAGE_A(t+1) writes the buffer whose readers all passed
// the (t-1)-end barrier; B-regs are private. Per-CU-per-k LDS load drops
// 4.1 KB (R8) -> 2.5 KB ~= 30 cyc vs 38.8 cyc MFMA — LDS no longer binding.
// A-swizzle (both sides, 0 conflicts measured R3-R8): 16-B chunk c of row r
// holds K-group c^(r&7).
// XCD chunking: XCD x covers ALL 32 brows x 2 bcols {2x,2x+1} -> B working
// set 2 MB L2-resident; A streams once to L3, re-read from L3 in round 2.
__device__ inline void gload16(const __bf16* g, const __bf16* l) {
  __builtin_amdgcn_global_load_lds(
      (const __attribute__((address_space(1))) void*)g,
      (__attribute__((address_space(3))) void*)l, 16, 0, 0);
}

#define MQ32(AV, BV)                                                         \
  {                                                                          \
    _Pragma("unroll") for (int mi = 0; mi < 4; ++mi)                         \
      _Pragma("unroll") for (int ni = 0; ni < 4; ++ni)                       \
        _Pragma("unroll") for (int kk = 0; kk < 2; ++kk)                     \
            accp[mi][ni] = __builtin_amdgcn_mfma_f32_16x16x32_bf16(          \
                AV[mi][kk], BV[ni][kk], accp[mi][ni], 0, 0, 0);              \
  }

__global__ __launch_bounds__(512, 2) void gemm_bt(
    const __bf16* __restrict__ A, const __bf16* __restrict__ Wbp,
    float* __restrict__ C) {
  extern __shared__ __bf16 lds[];  // 2 x 16384 elems, A only

  // XCD chunking: 32 brow x 2 bcol per XCD (B panel L2-resident)
  int bid = blockIdx.x;            // 0..511
  int x = bid & 7, idx = bid >> 3; // 64 blocks per XCD
  int brow = idx & 31;             // 0..31
  int bcol = (x << 1) | (idx >> 5);  // 0..15

  int tid = threadIdx.x, wid = tid >> 6, lane = tid & 63;
  int wm = wid & 1, wn = wid >> 1;   // 2M x 4N waves
  int lrow = lane & 15, lkhi = lane >> 4;

  const __bf16* Ab = A + (size_t)(brow * BM) * GK;

  // read-side swizzled chunk offsets (bytes within 128-B A row)
  int xr = lrow & 7;
  int offk0 = (lkhi ^ xr) * 16;
  int offk1 = ((4 + lkhi) ^ xr) * 16;
  const char* ldsc = (const char*)lds;
  int avbase = (wm * 128 + lrow) * 128;  // + mi*2048 + offk; buffers at 0 / 32768 B

  // A-stage: thread t covers row (t>>3)+64*li, chunk t&7, pre-swizzled source
  int grow = tid >> 3;
  int gcol = ((tid & 7) ^ (grow & 7)) * 8;

  // B: per-lane base into pre-fragmented Wbp; frag (ni,kk) of K-step tt at
  // + ni*65536 + (2*tt+kk)*512 elems (rt = bcol*16 + wn*4 + ni, kt = 2tt+kk)
  const __bf16* bw = Wbp + (size_t)(bcol * 16 + wn * 4) * 65536 + lane * 8;

  auto STAGE_A = [&](int kstep, int bufE) {
    const __bf16* s = Ab + (size_t)grow * GK + kstep * BK + gcol;
    const __bf16* d = lds + bufE + tid * 8;
    gload16(s, d);
    gload16(s + (size_t)64 * GK, d + 4096);
    gload16(s + (size_t)128 * GK, d + 8192);
    gload16(s + (size_t)192 * GK, d + 12288);
  };

  bf16x8 bvE[4][2], bvO[4][2];
  auto LOADB = [&](int tt, bf16x8 (&bv)[4][2]) {
#pragma unroll
    for (int ni = 0; ni < 4; ++ni) {
      bv[ni][0] = *(const bf16x8*)(bw + ni * 65536 + tt * 1024);
      bv[ni][1] = *(const bf16x8*)(bw + ni * 65536 + tt * 1024 + 512);
    }
  };

  f32x4 acc[8][4] = {};

  // prologue: A(0)->buf0; B(0)->bvE; B(1)->bvO; drain A0+B0, keep B1 in flight
  STAGE_A(0, 0);
  LOADB(0, bvE);
  LOADB(1, bvO);
  asm volatile("s_waitcnt vmcnt(8)" ::: "memory");
  __builtin_amdgcn_s_barrier();

  for (int t = 0; t < NSTEP; t += 2) {
    // ================= even K-step t (buf0, bvE) =================
    {
      if (t + 1 < NSTEP) STAGE_A(t + 1, 16384);
      bf16x8 a[4][2];
      f32x4(&accp)[8][4] = acc;  // alias for macro; use rows 0-3 then 4-7
#pragma unroll
      for (int mi = 0; mi < 4; ++mi) {
        a[mi][0] = *(const bf16x8*)(ldsc + avbase + mi * 2048 + offk0);
        a[mi][1] = *(const bf16x8*)(ldsc + avbase + mi * 2048 + offk1);
      }
#pragma unroll
      for (int mi = 0; mi < 4; ++mi)
#pragma unroll
        for (int ni = 0; ni < 4; ++ni)
#pragma unroll
          for (int kk = 0; kk < 2; ++kk)
            acc[mi][ni] = __builtin_amdgcn_mfma_f32_16x16x32_bf16(
                a[mi][kk], bvE[ni][kk], acc[mi][ni], 0, 0, 0);
#pragma unroll
      for (int mi = 0; mi < 4; ++mi) {
        a[mi][0] = *(const bf16x8*)(ldsc + avbase + (4 + mi) * 2048 + offk0);
        a[mi][1] = *(const bf16x8*)(ldsc + avbase + (4 + mi) * 2048 + offk1);
      }
#pragma unroll
      for (int mi = 0; mi < 4; ++mi)
#pragma unroll
        for (int ni = 0; ni < 4; ++ni)
#pragma unroll
          for (int kk = 0; kk < 2; ++kk)
            acc[4 + mi][ni] = __builtin_amdgcn_mfma_f32_16x16x32_bf16(
                a[mi][kk], bvE[ni][kk], acc[4 + mi][ni], 0, 0, 0);
      if (t + 2 < NSTEP) LOADB(t + 2, bvE);
      __builtin_amdgcn_sched_barrier(0);
      if (t + 2 < NSTEP)      asm volatile("s_waitcnt vmcnt(8)" ::: "memory");
      else                    asm volatile("s_waitcnt vmcnt(0)" ::: "memory");
      __builtin_amdgcn_s_barrier();
    }
    // ================= odd K-step t+1 (buf1, bvO) =================
    {
      if (t + 2 < NSTEP) STAGE_A(t + 2, 0);
      bf16x8 a[4][2];
#pragma unroll
      for (int mi = 0; mi < 4; ++mi) {
        a[mi][0] = *(const bf16x8*)(ldsc + 32768 + avbase + mi * 2048 + offk0);
        a[mi][1] = *(const bf16x8*)(ldsc + 32768 + avbase + mi * 2048 + offk1);
      }
#pragma unroll
      for (int mi = 0; mi < 4; ++mi)
#pragma unroll
        for (int ni = 0; ni < 4; ++ni)
#pragma unroll
          for (int kk = 0; kk < 2; ++kk)
            acc[mi][ni] = __builtin_amdgcn_mfma_f32_16x16x32_bf16(
                a[mi][kk], bvO[ni][kk], acc[mi][ni], 0, 0, 0);
#pragma unroll
      for (int mi = 0; mi < 4; ++mi) {
        a[mi][0] = *(const bf16x8*)(ldsc + 32768 + avbase + (4 + mi) * 2048 + offk0);
        a[mi][1] = *(const bf16x8*)(ldsc + 32768 + avbase + (4 + mi) * 2048 + offk1);
      }
#pragma unroll
      for (int mi = 0; mi < 4; ++mi)
#pragma unroll
        for (int ni = 0; ni < 4; ++ni)
#pragma unroll
          for (int kk = 0; kk < 2; ++kk)
            acc[4 + mi][ni] = __builtin_amdgcn_mfma_f32_16x16x32_bf16(
                a[mi][kk], bvO[ni][kk], acc[4 + mi][ni], 0, 0, 0);
      if (t + 3 < NSTEP) LOADB(t + 3, bvO);
      __builtin_amdgcn_sched_barrier(0);
      if (t + 3 < NSTEP) {
        asm volatile("s_waitcnt vmcnt(8)" ::: "memory");
        __builtin_amdgcn_s_barrier();
      } else if (t + 2 < NSTEP) {
        asm volatile("s_waitcnt vmcnt(0)" ::: "memory");
        __builtin_amdgcn_s_barrier();
      }
      // t+1 == NSTEP-1: fall through to epilogue, no wait needed
    }
  }

  // epilogue: C/D layout (16x16x32 bf16): col = lane&15, row = (lane>>4)*4 + r
  int crow0 = brow * BM + wm * 128;
  int ccol0 = bcol * BN + wn * 64;
#pragma unroll
  for (int mi = 0; mi < 8; ++mi)
#pragma unroll
    for (int ni = 0; ni < 4; ++ni) {
      int col = ccol0 + ni * 16 + lrow;
#pragma unroll
      for (int r = 0; r < 4; ++r) {
        int row = crow0 + mi * 16 + lkhi * 4 + r;
        C[(size_t)row * GN + col] = acc[mi][ni][r];
      }
    }
}

// -------------------- fused out_scale/bias + LayerNorm (in place) --------------------
__global__ __launch_bounds__(256) void ln_fuse(
    float* __restrict__ h, const float* __restrict__ os,
    const float* __restrict__ bs, const float* __restrict__ g,
    const float* __restrict__ be) {
  constexpr int N = GN;  // 4096
  int row = blockIdx.x;
  float* hr = h + (size_t)row * N;
  int t = threadIdx.x;

  float v[16];
  float sum = 0.f, ssq = 0.f;
#pragma unroll
  for (int c = 0; c < 4; ++c) {
    int idx = c * 1024 + t * 4;
    float4 hv = *(const float4*)(hr + idx);
    float4 sv = *(const float4*)(os + idx);
    float4 bv = *(const float4*)(bs + idx);
    float a0 = hv.x * sv.x + bv.x;
    float a1 = hv.y * sv.y + bv.y;
    float a2 = hv.z * sv.z + bv.z;
    float a3 = hv.w * sv.w + bv.w;
    v[c * 4 + 0] = a0; v[c * 4 + 1] = a1; v[c * 4 + 2] = a2; v[c * 4 + 3] = a3;
    sum += a0 + a1 + a2 + a3;
    ssq += a0 * a0 + a1 * a1 + a2 * a2 + a3 * a3;
  }

  // wave64 reduce
#pragma unroll
  for (int off = 32; off > 0; off >>= 1) {
    sum += __shfl_down(sum, off);
    ssq += __shfl_down(ssq, off);
  }
  __shared__ float rs[8];
  int wid = t >> 6, lane = t & 63;
  if (lane == 0) { rs[wid] = sum; rs[4 + wid] = ssq; }
  __syncthreads();
  sum = rs[0] + rs[1] + rs[2] + rs[3];
  ssq = rs[4] + rs[5] + rs[6] + rs[7];

  float mean = sum * (1.f / N);
  float var = ssq * (1.f / N) - mean * mean;
  float rstd = rsqrtf(var + 1e-5f);

#pragma unroll
  for (int c = 0; c < 4; ++c) {
    int idx = c * 1024 + t * 4;
    float4 gv = *(const float4*)(g + idx);
    float4 bev = *(const float4*)(be + idx);
    float4 o;
    o.x = (v[c * 4 + 0] - mean) * rstd * gv.x + bev.x;
    o.y = (v[c * 4 + 1] - mean) * rstd * gv.y + bev.y;
    o.z = (v[c * 4 + 2] - mean) * rstd * gv.z + bev.z;
    o.w = (v[c * 4 + 3] - mean) * rstd * gv.w + bev.w;
    *(float4*)(hr + idx) = o;
  }
}

extern "C" void kernel_launch(void* const* d_in, const int* in_sizes, int n_in,
                              void* d_out, int out_size, void* d_ws, size_t ws_size,
                              hipStream_t stream) {
  const float* x      = (const float*)d_in[0];  // [4,2048,4096]
  const float* w      = (const float*)d_in[1];  // [4096,4096]
  const float* iscale = (const float*)d_in[2];  // [4096]
  const float* oscale = (const float*)d_in[3];  // [4096]
  const float* bias   = (const float*)d_in[4];  // [4096]
  const float* gamma  = (const float*)d_in[5];  // [4096]
  const float* beta   = (const float*)d_in[6];  // [4096]
  float* out = (float*)d_out;                   // [8192,4096] f32

  __bf16* Abf = (__bf16*)d_ws;                                   // 67 MB
  __bf16* Wbp = (__bf16*)((char*)d_ws + (size_t)GM * GK * 2);    // 33.5 MB

  (void)hipFuncSetAttribute((const void*)gemm_bt,
                            hipFuncAttributeMaxDynamicSharedMemorySize, LDS_BYTES);

  prep_x_kernel<<<(GM * GK) / (256 * 8), 256, 0, stream>>>(x, iscale, Abf);
  prep_w_kernel<<<(GN * GK) / (256 * 8), 256, 0, stream>>>(w, Wbp);
  gemm_bt<<<(GM / BM) * (GN / BN), 512, LDS_BYTES, stream>>>(Abf, Wbp, out);
  ln_fuse<<<GM, 256, 0, stream>>>(out, oscale, bias, gamma, beta);
}